// Round 6
// baseline (424.734 us; speedup 1.0000x reference)
//
#include <hip/hip_runtime.h>
#include <hip/hip_bf16.h>

#define NHEAD 16
#define HDIM 64
#define DINNER 1024
#define NBATCH 4
#define SEQ 2048
#define NTOK (NBATCH*SEQ)   // 8192

typedef __bf16 bf16;
typedef __bf16 bf16x4 __attribute__((ext_vector_type(4)));
typedef __bf16 bf16x8 __attribute__((ext_vector_type(8)));
typedef float f32x4 __attribute__((ext_vector_type(4)));

// workspace layout (bf16 element offsets)
#define OFF_BO   8
#define OFF_XB   128
#define OFF_WQT  (OFF_XB + NTOK*HDIM)
#define OFF_WKT  (OFF_WQT + DINNER*HDIM)
#define OFF_WVT  (OFF_WKT + DINNER*HDIM)
#define OFF_WOT  (OFF_WVT + DINNER*HDIM)
#define OFF_Q    (OFF_WOT + DINNER*HDIM)
#define OFF_K    (OFF_Q + NTOK*DINNER)
#define OFF_VT   (OFF_K + NTOK*DINNER)
#define OFF_ATT  (OFF_VT + NTOK*DINNER)

// raw-score domain; exp2((s - m) * SSCALE) == exp((s - m)/8)
#define SSCALE 0.18033688011112042f
#define MASKVAL (-3.0e8f)

static __device__ __forceinline__ bf16x8 ld8(const bf16* p) {
  return *reinterpret_cast<const bf16x8*>(p);
}

// ---------------- kernel 0: runtime input-dtype detection ------------------
__global__ __launch_bounds__(64) void detect_kernel(const unsigned short* __restrict__ xb,
                                                    int* __restrict__ flag) {
  int lane = threadIdx.x;
  bool ok = true;
  for (int i = 0; i < 8; i++) {
    unsigned e = (xb[lane * 8 + i] >> 7) & 0xFF;
    ok = ok && (e >= 64 && e <= 140);
  }
  unsigned long long m = __ballot(ok);
  if (lane == 0) *flag = (m == ~0ull) ? 1 : 0;
}

// ---------------- kernel 1: normalize inputs into ws (bf16) ----------------
__global__ __launch_bounds__(256) void prep_kernel(
    const void* __restrict__ x, const void* __restrict__ Wq,
    const void* __restrict__ Wk, const void* __restrict__ Wv,
    const void* __restrict__ Wo, const void* __restrict__ bo,
    const int* __restrict__ flag, bf16* __restrict__ ws) {
  int isbf = *flag;
  int z = blockIdx.y;
  int idx = blockIdx.x * 256 + threadIdx.x;
  if (z < 3) {
    const void* src = (z == 0) ? Wq : (z == 1) ? Wk : Wv;
    bf16* dst = ws + ((z == 0) ? OFF_WQT : (z == 1) ? OFF_WKT : OFF_WVT);
    int n = idx >> 6, d = idx & 63;
    int i = d * DINNER + n;
    dst[n * HDIM + d] = isbf ? ((const bf16*)src)[i] : (bf16)((const float*)src)[i];
  } else if (z == 3) {
    int n = idx >> 10, k = idx & 1023;
    int i = k * HDIM + n;
    ws[OFF_WOT + n * DINNER + k] = isbf ? ((const bf16*)Wo)[i] : (bf16)((const float*)Wo)[i];
  } else if (z < 12) {
    int i = (z - 4) * 65536 + idx;
    ws[OFF_XB + i] = isbf ? ((const bf16*)x)[i] : (bf16)((const float*)x)[i];
  } else {
    if (idx < 64) ws[OFF_BO + idx] = isbf ? ((const bf16*)bo)[idx] : (bf16)((const float*)bo)[idx];
  }
}

// ---------------- kernel 2: fused QKV projection ---------------------------
// 64 tokens per wave (W-frags reused 4x). grid (128, 4, 3), block 256.
// pz<2: C[token][n] (A=x, B=W); pz==2: C[n][token] (A=W, B=x) -> V^T.
__global__ __launch_bounds__(256) void qkv_kernel(bf16* __restrict__ ws) {
  int tt = blockIdx.x, pz = blockIdx.z;
  int nc = blockIdx.y * 4 + (threadIdx.x >> 6);
  int lane = threadIdx.x & 63;
  int lq = lane & 15, quad = lane >> 4;
  const bf16* WT = ws + OFF_WQT + pz * (DINNER * HDIM);
  int n0 = nc * 64;
  bf16x8 w0[4], w1[4];
#pragma unroll
  for (int c = 0; c < 4; c++) {
    const bf16* wr = WT + (n0 + c * 16 + lq) * HDIM;
    w0[c] = ld8(wr + quad * 8);
    w1[c] = ld8(wr + 32 + quad * 8);
  }
  if (pz < 2) {
    bf16* P = ws + (pz == 0 ? OFF_Q : OFF_K);
#pragma unroll
    for (int mi = 0; mi < 4; mi++) {
      int t0 = tt * 64 + mi * 16;
      const bf16* xrow = ws + OFF_XB + (t0 + lq) * HDIM;
      bf16x8 x0 = ld8(xrow + quad * 8);
      bf16x8 x1 = ld8(xrow + 32 + quad * 8);
#pragma unroll
      for (int c = 0; c < 4; c++) {
        f32x4 z = {0.f, 0.f, 0.f, 0.f};
        z = __builtin_amdgcn_mfma_f32_16x16x32_bf16(x0, w0[c], z, 0, 0, 0);
        z = __builtin_amdgcn_mfma_f32_16x16x32_bf16(x1, w1[c], z, 0, 0, 0);
        int n = n0 + c * 16 + lq;
        int h = n >> 6, d = n & 63;
#pragma unroll
        for (int r = 0; r < 4; r++) {
          int t = t0 + quad * 4 + r;
          int b = t >> 11, s = t & (SEQ - 1);
          P[((b * NHEAD + h) * SEQ + s) * HDIM + d] = (bf16)z[r];
        }
      }
    }
  } else {
    bf16* VTb = ws + OFF_VT;
#pragma unroll
    for (int mi = 0; mi < 4; mi++) {
      int t0 = tt * 64 + mi * 16;
      const bf16* xrow = ws + OFF_XB + (t0 + lq) * HDIM;
      bf16x8 x0 = ld8(xrow + quad * 8);
      bf16x8 x1 = ld8(xrow + 32 + quad * 8);
      int b = t0 >> 11, s0 = t0 & (SEQ - 1);
#pragma unroll
      for (int c = 0; c < 4; c++) {
        f32x4 z = {0.f, 0.f, 0.f, 0.f};
        z = __builtin_amdgcn_mfma_f32_16x16x32_bf16(w0[c], x0, z, 0, 0, 0);
        z = __builtin_amdgcn_mfma_f32_16x16x32_bf16(w1[c], x1, z, 0, 0, 0);
#pragma unroll
        for (int r = 0; r < 4; r++) {
          int n = n0 + c * 16 + quad * 4 + r;
          int h = n >> 6, d = n & 63;
          VTb[(((size_t)b * NHEAD + h) * HDIM + d) * SEQ + s0 + lq] = (bf16)z[r];
        }
      }
    }
  }
}

// ---------------- kernel 3: flash attention, key-split ---------------------
// grid 4096 blocks x 128 thr (2 waves). Block owns 32 queries; wave 0 takes
// front half of key tiles, wave 1 back half; exact fp32 merge through LDS.
// 8192 waves total = 32 waves/CU; VGPR capped 64 -> full occupancy.
__global__ __launch_bounds__(128, 8) void flash_kernel(const int* __restrict__ cmask,
                                                       bf16* __restrict__ ws) {
  __shared__ __align__(16) bf16 Pl[2 * 2 * 16 * 72];  // per-wave [2][16][72]
  int bid = blockIdx.x;
  int bh = bid & 63;
  int qi = bid >> 6;
  int qw = (63 - qi) * 32;                // qi=0 dispatched first = longest
  int widx = threadIdx.x >> 6;            // 0 = front tiles, 1 = back tiles
  int lane = threadIdx.x & 63;
  int lq = lane & 15, quad = lane >> 4;
  int causal = cmask[0];
  const bf16* Q = ws + OFF_Q + (size_t)bh * SEQ * HDIM;
  const bf16* K = ws + OFF_K + (size_t)bh * SEQ * HDIM;
  const bf16* VT = ws + OFF_VT + (size_t)bh * HDIM * SEQ;

  // Q as B-operand (cols=queries)
  bf16x8 bq[2][2];
#pragma unroll
  for (int m = 0; m < 2; m++) {
    const bf16* qrow = Q + (qw + m * 16 + lq) * HDIM;
    bq[m][0] = ld8(qrow + quad * 8);
    bq[m][1] = ld8(qrow + 32 + quad * 8);
  }

  f32x4 o[2][4];   // O^T accumulators
  float mm[2], ll[2];
#pragma unroll
  for (int m = 0; m < 2; m++) {
    mm[m] = -__builtin_inff(); ll[m] = 0.f;
#pragma unroll
    for (int c = 0; c < 4; c++) o[m][c] = (f32x4){0.f, 0.f, 0.f, 0.f};
  }

  int T = causal ? ((qw + 31) / 64 + 1) : (SEQ / 64);
  int Th = (T + 1) >> 1;
  int tbeg = widx ? Th : 0;
  int tend = widx ? T : Th;
  int plb = widx * (2 * 16 * 72);

  for (int ti = tbeg; ti < tend; ti++) {
    int k0 = ti * 64;
    // ---- S^T: K rows as A-operand, transient per t-subtile
    f32x4 st[2][4];
#pragma unroll
    for (int t = 0; t < 4; t++) {
      const bf16* kr = K + (k0 + t * 16 + lq) * HDIM;
      bf16x8 a0 = ld8(kr + quad * 8);
      bf16x8 a1 = ld8(kr + 32 + quad * 8);
#pragma unroll
      for (int m = 0; m < 2; m++) {
        f32x4 z = {0.f, 0.f, 0.f, 0.f};
        z = __builtin_amdgcn_mfma_f32_16x16x32_bf16(a0, bq[m][0], z, 0, 0, 0);
        z = __builtin_amdgcn_mfma_f32_16x16x32_bf16(a1, bq[m][1], z, 0, 0, 0);
        st[m][t] = z;
      }
    }
    bool needmask = causal && (k0 + 63 > qw);
    float al2[2];
#pragma unroll
    for (int m = 0; m < 2; m++) {
      if (needmask) {
        int qrel = qw + m * 16 + lq - k0 - quad * 4;  // key t*16+r masked if > qrel
#pragma unroll
        for (int t = 0; t < 4; t++)
#pragma unroll
          for (int r = 0; r < 4; r++)
            if (t * 16 + r > qrel) st[m][t][r] = MASKVAL;
      }
      // in-lane max over 16 (ILP tree) + 2 cross-quad shuffles
      float x0 = fmaxf(fmaxf(st[m][0][0], st[m][0][1]), fmaxf(st[m][0][2], st[m][0][3]));
      float x1 = fmaxf(fmaxf(st[m][1][0], st[m][1][1]), fmaxf(st[m][1][2], st[m][1][3]));
      float x2 = fmaxf(fmaxf(st[m][2][0], st[m][2][1]), fmaxf(st[m][2][2], st[m][2][3]));
      float x3 = fmaxf(fmaxf(st[m][3][0], st[m][3][1]), fmaxf(st[m][3][2], st[m][3][3]));
      float mx = fmaxf(fmaxf(x0, x1), fmaxf(x2, x3));
      mx = fmaxf(mx, __shfl_xor(mx, 16));
      mx = fmaxf(mx, __shfl_xor(mx, 32));
      float mn = fmaxf(mm[m], mx);
      float al = exp2f((mm[m] - mn) * SSCALE);
      float mnS = mn * SSCALE;
      float sum = 0.f;
#pragma unroll
      for (int t = 0; t < 4; t++) {        // fused exp + sum + pack + LDS write
        float e0 = exp2f(fmaf(st[m][t][0], SSCALE, -mnS));
        float e1 = exp2f(fmaf(st[m][t][1], SSCALE, -mnS));
        float e2 = exp2f(fmaf(st[m][t][2], SSCALE, -mnS));
        float e3 = exp2f(fmaf(st[m][t][3], SSCALE, -mnS));
        sum += (e0 + e1) + (e2 + e3);
        bf16x4 pk = {(bf16)e0, (bf16)e1, (bf16)e2, (bf16)e3};
        *reinterpret_cast<bf16x4*>(&Pl[plb + m * 16 * 72 + lq * 72 + t * 16 + quad * 4]) = pk;
      }
      sum += __shfl_xor(sum, 16);
      sum += __shfl_xor(sum, 32);
      ll[m] = ll[m] * al + sum;
      mm[m] = mn;
      al2[m] = al;
    }
#pragma unroll
    for (int m = 0; m < 2; m++)
#pragma unroll
      for (int c = 0; c < 4; c++)
#pragma unroll
        for (int r = 0; r < 4; r++) o[m][c][r] *= al2[m];
    // ---- PV: P^T from per-wave LDS as B-operand; V^T rows as A (transient)
    bf16x8 bp[2][2];
#pragma unroll
    for (int m = 0; m < 2; m++) {
      bp[m][0] = ld8(&Pl[plb + m * 16 * 72 + lq * 72 + quad * 8]);
      bp[m][1] = ld8(&Pl[plb + m * 16 * 72 + lq * 72 + 32 + quad * 8]);
    }
#pragma unroll
    for (int c = 0; c < 4; c++) {
      const bf16* vr = VT + (c * 16 + lq) * SEQ + k0;
      bf16x8 av0 = ld8(vr + quad * 8);
      bf16x8 av1 = ld8(vr + 32 + quad * 8);
#pragma unroll
      for (int m = 0; m < 2; m++) {
        o[m][c] = __builtin_amdgcn_mfma_f32_16x16x32_bf16(av0, bp[m][0], o[m][c], 0, 0, 0);
        o[m][c] = __builtin_amdgcn_mfma_f32_16x16x32_bf16(av1, bp[m][1], o[m][c], 0, 0, 0);
      }
    }
  }
  // ---- merge wave1 -> wave0 (exact fp32), two phases through wave1's Pl ----
  float* mrg = reinterpret_cast<float*>(&Pl[2 * 16 * 72]);  // 4096B o + 128B ml
  float* mlf = mrg + 1024;
  bf16* ar = ws + OFF_ATT;
  int b = bh >> 4, h = bh & 15;
#pragma unroll
  for (int m = 0; m < 2; m++) {
    if (widx == 1) {
#pragma unroll
      for (int c = 0; c < 4; c++)
        *reinterpret_cast<f32x4*>(&mrg[(c * 64 + lane) * 4]) = o[m][c];
      if (quad == 0) { mlf[lq * 2] = mm[m]; mlf[lq * 2 + 1] = ll[m]; }
    }
    __syncthreads();
    if (widx == 0) {
      float mB = mlf[lq * 2], lB = mlf[lq * 2 + 1];
      float mn = fmaxf(mm[m], mB);
      float a = exp2f((mm[m] - mn) * SSCALE);
      float bb = exp2f((mB - mn) * SSCALE);
      float linv = 1.0f / (ll[m] * a + lB * bb);
      size_t rowoff = ((size_t)(b * SEQ + qw + m * 16 + lq)) * DINNER + h * HDIM;
#pragma unroll
      for (int c = 0; c < 4; c++) {
        f32x4 ob = *reinterpret_cast<f32x4*>(&mrg[(c * 64 + lane) * 4]);
        bf16x4 ov = {(bf16)((o[m][c][0] * a + ob[0] * bb) * linv),
                     (bf16)((o[m][c][1] * a + ob[1] * bb) * linv),
                     (bf16)((o[m][c][2] * a + ob[2] * bb) * linv),
                     (bf16)((o[m][c][3] * a + ob[3] * bb) * linv)};
        *reinterpret_cast<bf16x4*>(&ar[rowoff + c * 16 + quad * 4]) = ov;
      }
    }
    __syncthreads();
  }
}

// ---------------- kernel 4: output projection, 4-wave split-K --------------
__global__ __launch_bounds__(256) void oproj_kernel(const bf16* __restrict__ ws,
                                                    const int* __restrict__ flag,
                                                    void* __restrict__ outp) {
  __shared__ __align__(16) float red[3 * 64 * 16];  // 12 KB
  int isbf = *flag;
  int tt = blockIdx.x;
  int w = threadIdx.x >> 6;
  int lane = threadIdx.x & 63;
  int lq = lane & 15, quad = lane >> 4;
  const bf16* A = ws + OFF_ATT + (size_t)(tt * 16 + lq) * DINNER;
  const bf16* WoT = ws + OFF_WOT;
  f32x4 acc[4];
#pragma unroll
  for (int c = 0; c < 4; c++) acc[c] = (f32x4){0.f, 0.f, 0.f, 0.f};
  int kbeg = w * 256;
  for (int k0 = kbeg; k0 < kbeg + 256; k0 += 32) {
    bf16x8 a = ld8(A + k0 + quad * 8);
#pragma unroll
    for (int c = 0; c < 4; c++) {
      bf16x8 b = ld8(WoT + (size_t)(c * 16 + lq) * DINNER + k0 + quad * 8);
      acc[c] = __builtin_amdgcn_mfma_f32_16x16x32_bf16(a, b, acc[c], 0, 0, 0);
    }
  }
  if (w > 0) {
#pragma unroll
    for (int c = 0; c < 4; c++)
      *reinterpret_cast<f32x4*>(&red[(((w - 1) * 64 + lane) * 4 + c) * 4]) = acc[c];
  }
  __syncthreads();
  if (w == 0) {
#pragma unroll
    for (int j = 0; j < 3; j++)
#pragma unroll
      for (int c = 0; c < 4; c++)
        acc[c] += *reinterpret_cast<f32x4*>(&red[((j * 64 + lane) * 4 + c) * 4]);
#pragma unroll
    for (int c = 0; c < 4; c++) {
      float bv = (float)ws[OFF_BO + c * 16 + lq];
#pragma unroll
      for (int r = 0; r < 4; r++) {
        int t = tt * 16 + quad * 4 + r;
        float v = acc[c][r] + bv;
        size_t oo = (size_t)t * HDIM + c * 16 + lq;
        if (isbf) ((bf16*)outp)[oo] = (bf16)v;
        else      ((float*)outp)[oo] = v;
      }
    }
  }
}

extern "C" void kernel_launch(void* const* d_in, const int* in_sizes, int n_in,
                              void* d_out, int out_size, void* d_ws, size_t ws_size,
                              hipStream_t stream) {
  const void* x  = d_in[0];
  const void* Wq = d_in[1];
  const void* Wk = d_in[2];
  const void* Wv = d_in[3];
  const void* Wo = d_in[4];
  const void* bo = d_in[5];
  const int* cm  = (const int*)d_in[6];
  bf16* ws = (bf16*)d_ws;
  int* flag = (int*)d_ws;

  hipLaunchKernelGGL(detect_kernel, dim3(1), dim3(64), 0, stream,
                     (const unsigned short*)x, flag);
  hipLaunchKernelGGL(prep_kernel, dim3(256, 13), dim3(256), 0, stream,
                     x, Wq, Wk, Wv, Wo, bo, flag, ws);
  hipLaunchKernelGGL(qkv_kernel, dim3(128, 4, 3), dim3(256), 0, stream, ws);
  hipLaunchKernelGGL(flash_kernel, dim3(4096), dim3(128), 0, stream, cm, ws);
  hipLaunchKernelGGL(oproj_kernel, dim3(512), dim3(256), 0, stream, ws, flag, d_out);
}

// Round 7
// 231.515 us; speedup vs baseline: 1.8346x; 1.8346x over previous
//
#include <hip/hip_runtime.h>
#include <hip/hip_bf16.h>

#define NHEAD 16
#define HDIM 64
#define DINNER 1024
#define NBATCH 4
#define SEQ 2048
#define NTOK (NBATCH*SEQ)   // 8192

typedef __bf16 bf16;
typedef __bf16 bf16x4 __attribute__((ext_vector_type(4)));
typedef __bf16 bf16x8 __attribute__((ext_vector_type(8)));
typedef float f32x4 __attribute__((ext_vector_type(4)));

// workspace layout (bf16 element offsets)
#define OFF_BO   8
#define OFF_XB   128
#define OFF_WQT  (OFF_XB + NTOK*HDIM)
#define OFF_WKT  (OFF_WQT + DINNER*HDIM)
#define OFF_WVT  (OFF_WKT + DINNER*HDIM)
#define OFF_WOT  (OFF_WVT + DINNER*HDIM)
#define OFF_Q    (OFF_WOT + DINNER*HDIM)
#define OFF_K    (OFF_Q + NTOK*DINNER)
#define OFF_VT   (OFF_K + NTOK*DINNER)
#define OFF_ATT  (OFF_VT + NTOK*DINNER)

// raw-score domain; exp2((s - m) * SSCALE) == exp((s - m)/8)
#define SSCALE 0.18033688011112042f
#define MASKVAL (-3.0e8f)

static __device__ __forceinline__ bf16x8 ld8(const bf16* p) {
  return *reinterpret_cast<const bf16x8*>(p);
}

// ---------------- kernel 0: runtime input-dtype detection ------------------
__global__ __launch_bounds__(64) void detect_kernel(const unsigned short* __restrict__ xb,
                                                    int* __restrict__ flag) {
  int lane = threadIdx.x;
  bool ok = true;
  for (int i = 0; i < 8; i++) {
    unsigned e = (xb[lane * 8 + i] >> 7) & 0xFF;
    ok = ok && (e >= 64 && e <= 140);
  }
  unsigned long long m = __ballot(ok);
  if (lane == 0) *flag = (m == ~0ull) ? 1 : 0;
}

// ---------------- kernel 1: normalize inputs into ws (bf16) ----------------
__global__ __launch_bounds__(256) void prep_kernel(
    const void* __restrict__ x, const void* __restrict__ Wq,
    const void* __restrict__ Wk, const void* __restrict__ Wv,
    const void* __restrict__ Wo, const void* __restrict__ bo,
    const int* __restrict__ flag, bf16* __restrict__ ws) {
  int isbf = *flag;
  int z = blockIdx.y;
  int idx = blockIdx.x * 256 + threadIdx.x;
  if (z < 3) {
    const void* src = (z == 0) ? Wq : (z == 1) ? Wk : Wv;
    bf16* dst = ws + ((z == 0) ? OFF_WQT : (z == 1) ? OFF_WKT : OFF_WVT);
    int n = idx >> 6, d = idx & 63;
    int i = d * DINNER + n;
    dst[n * HDIM + d] = isbf ? ((const bf16*)src)[i] : (bf16)((const float*)src)[i];
  } else if (z == 3) {
    int n = idx >> 10, k = idx & 1023;
    int i = k * HDIM + n;
    ws[OFF_WOT + n * DINNER + k] = isbf ? ((const bf16*)Wo)[i] : (bf16)((const float*)Wo)[i];
  } else if (z < 12) {
    int i = (z - 4) * 65536 + idx;
    ws[OFF_XB + i] = isbf ? ((const bf16*)x)[i] : (bf16)((const float*)x)[i];
  } else {
    if (idx < 64) ws[OFF_BO + idx] = isbf ? ((const bf16*)bo)[idx] : (bf16)((const float*)bo)[idx];
  }
}

// ---------------- kernel 2: fused QKV projection ---------------------------
// 64 tokens per wave (W-frags reused 4x). grid (128, 4, 3), block 256.
// pz<2: C[token][n] (A=x, B=W); pz==2: C[n][token] (A=W, B=x) -> V^T.
__global__ __launch_bounds__(256) void qkv_kernel(bf16* __restrict__ ws) {
  int tt = blockIdx.x, pz = blockIdx.z;
  int nc = blockIdx.y * 4 + (threadIdx.x >> 6);
  int lane = threadIdx.x & 63;
  int lq = lane & 15, quad = lane >> 4;
  const bf16* WT = ws + OFF_WQT + pz * (DINNER * HDIM);
  int n0 = nc * 64;
  bf16x8 w0[4], w1[4];
#pragma unroll
  for (int c = 0; c < 4; c++) {
    const bf16* wr = WT + (n0 + c * 16 + lq) * HDIM;
    w0[c] = ld8(wr + quad * 8);
    w1[c] = ld8(wr + 32 + quad * 8);
  }
  if (pz < 2) {
    bf16* P = ws + (pz == 0 ? OFF_Q : OFF_K);
#pragma unroll
    for (int mi = 0; mi < 4; mi++) {
      int t0 = tt * 64 + mi * 16;
      const bf16* xrow = ws + OFF_XB + (t0 + lq) * HDIM;
      bf16x8 x0 = ld8(xrow + quad * 8);
      bf16x8 x1 = ld8(xrow + 32 + quad * 8);
#pragma unroll
      for (int c = 0; c < 4; c++) {
        f32x4 z = {0.f, 0.f, 0.f, 0.f};
        z = __builtin_amdgcn_mfma_f32_16x16x32_bf16(x0, w0[c], z, 0, 0, 0);
        z = __builtin_amdgcn_mfma_f32_16x16x32_bf16(x1, w1[c], z, 0, 0, 0);
        int n = n0 + c * 16 + lq;
        int h = n >> 6, d = n & 63;
#pragma unroll
        for (int r = 0; r < 4; r++) {
          int t = t0 + quad * 4 + r;
          int b = t >> 11, s = t & (SEQ - 1);
          P[((b * NHEAD + h) * SEQ + s) * HDIM + d] = (bf16)z[r];
        }
      }
    }
  } else {
    bf16* VTb = ws + OFF_VT;
#pragma unroll
    for (int mi = 0; mi < 4; mi++) {
      int t0 = tt * 64 + mi * 16;
      const bf16* xrow = ws + OFF_XB + (t0 + lq) * HDIM;
      bf16x8 x0 = ld8(xrow + quad * 8);
      bf16x8 x1 = ld8(xrow + 32 + quad * 8);
      int b = t0 >> 11, s0 = t0 & (SEQ - 1);
#pragma unroll
      for (int c = 0; c < 4; c++) {
        f32x4 z = {0.f, 0.f, 0.f, 0.f};
        z = __builtin_amdgcn_mfma_f32_16x16x32_bf16(w0[c], x0, z, 0, 0, 0);
        z = __builtin_amdgcn_mfma_f32_16x16x32_bf16(w1[c], x1, z, 0, 0, 0);
#pragma unroll
        for (int r = 0; r < 4; r++) {
          int n = n0 + c * 16 + quad * 4 + r;
          int h = n >> 6, d = n & 63;
          VTb[(((size_t)b * NHEAD + h) * HDIM + d) * SEQ + s0 + lq] = (bf16)z[r];
        }
      }
    }
  }
}

// ---------------- kernel 3: flash attention, key-split ---------------------
// grid 4096 blocks x 128 thr (2 waves). Block owns 32 queries; wave 0 takes
// front half of key tiles, wave 1 back half; exact fp32 merge through LDS.
// 8192 waves total = 32/CU possible. launch_bounds min-waves=4 (VGPR cap
// 128): round 6's (128,8) forced VGPR=32 -> 1.5 GB scratch spills, 2.3x
// slower. Body compiles at ~64 VGPR naturally, which permits 8 waves/EU.
__global__ __launch_bounds__(128, 4) void flash_kernel(const int* __restrict__ cmask,
                                                       bf16* __restrict__ ws) {
  __shared__ __align__(16) bf16 Pl[2 * 2 * 16 * 72];  // per-wave [2][16][72]
  int bid = blockIdx.x;
  int bh = bid & 63;
  int qi = bid >> 6;
  int qw = (63 - qi) * 32;                // qi=0 dispatched first = longest
  int widx = threadIdx.x >> 6;            // 0 = front tiles, 1 = back tiles
  int lane = threadIdx.x & 63;
  int lq = lane & 15, quad = lane >> 4;
  int causal = cmask[0];
  const bf16* Q = ws + OFF_Q + (size_t)bh * SEQ * HDIM;
  const bf16* K = ws + OFF_K + (size_t)bh * SEQ * HDIM;
  const bf16* VT = ws + OFF_VT + (size_t)bh * HDIM * SEQ;

  // Q as B-operand (cols=queries)
  bf16x8 bq[2][2];
#pragma unroll
  for (int m = 0; m < 2; m++) {
    const bf16* qrow = Q + (qw + m * 16 + lq) * HDIM;
    bq[m][0] = ld8(qrow + quad * 8);
    bq[m][1] = ld8(qrow + 32 + quad * 8);
  }

  f32x4 o[2][4];   // O^T accumulators
  float mm[2], ll[2];
#pragma unroll
  for (int m = 0; m < 2; m++) {
    mm[m] = -__builtin_inff(); ll[m] = 0.f;
#pragma unroll
    for (int c = 0; c < 4; c++) o[m][c] = (f32x4){0.f, 0.f, 0.f, 0.f};
  }

  int T = causal ? ((qw + 31) / 64 + 1) : (SEQ / 64);
  int Th = (T + 1) >> 1;
  int tbeg = widx ? Th : 0;
  int tend = widx ? T : Th;
  int plb = widx * (2 * 16 * 72);

  for (int ti = tbeg; ti < tend; ti++) {
    int k0 = ti * 64;
    // ---- S^T: K rows as A-operand, transient per t-subtile
    f32x4 st[2][4];
#pragma unroll
    for (int t = 0; t < 4; t++) {
      const bf16* kr = K + (k0 + t * 16 + lq) * HDIM;
      bf16x8 a0 = ld8(kr + quad * 8);
      bf16x8 a1 = ld8(kr + 32 + quad * 8);
#pragma unroll
      for (int m = 0; m < 2; m++) {
        f32x4 z = {0.f, 0.f, 0.f, 0.f};
        z = __builtin_amdgcn_mfma_f32_16x16x32_bf16(a0, bq[m][0], z, 0, 0, 0);
        z = __builtin_amdgcn_mfma_f32_16x16x32_bf16(a1, bq[m][1], z, 0, 0, 0);
        st[m][t] = z;
      }
    }
    bool needmask = causal && (k0 + 63 > qw);
    float al2[2];
#pragma unroll
    for (int m = 0; m < 2; m++) {
      if (needmask) {
        int qrel = qw + m * 16 + lq - k0 - quad * 4;  // key t*16+r masked if > qrel
#pragma unroll
        for (int t = 0; t < 4; t++)
#pragma unroll
          for (int r = 0; r < 4; r++)
            if (t * 16 + r > qrel) st[m][t][r] = MASKVAL;
      }
      // in-lane max over 16 (ILP tree) + 2 cross-quad shuffles
      float x0 = fmaxf(fmaxf(st[m][0][0], st[m][0][1]), fmaxf(st[m][0][2], st[m][0][3]));
      float x1 = fmaxf(fmaxf(st[m][1][0], st[m][1][1]), fmaxf(st[m][1][2], st[m][1][3]));
      float x2 = fmaxf(fmaxf(st[m][2][0], st[m][2][1]), fmaxf(st[m][2][2], st[m][2][3]));
      float x3 = fmaxf(fmaxf(st[m][3][0], st[m][3][1]), fmaxf(st[m][3][2], st[m][3][3]));
      float mx = fmaxf(fmaxf(x0, x1), fmaxf(x2, x3));
      mx = fmaxf(mx, __shfl_xor(mx, 16));
      mx = fmaxf(mx, __shfl_xor(mx, 32));
      float mn = fmaxf(mm[m], mx);
      float al = exp2f((mm[m] - mn) * SSCALE);
      float mnS = mn * SSCALE;
      float sum = 0.f;
#pragma unroll
      for (int t = 0; t < 4; t++) {        // fused exp + sum + pack + LDS write
        float e0 = exp2f(fmaf(st[m][t][0], SSCALE, -mnS));
        float e1 = exp2f(fmaf(st[m][t][1], SSCALE, -mnS));
        float e2 = exp2f(fmaf(st[m][t][2], SSCALE, -mnS));
        float e3 = exp2f(fmaf(st[m][t][3], SSCALE, -mnS));
        sum += (e0 + e1) + (e2 + e3);
        bf16x4 pk = {(bf16)e0, (bf16)e1, (bf16)e2, (bf16)e3};
        *reinterpret_cast<bf16x4*>(&Pl[plb + m * 16 * 72 + lq * 72 + t * 16 + quad * 4]) = pk;
      }
      sum += __shfl_xor(sum, 16);
      sum += __shfl_xor(sum, 32);
      ll[m] = ll[m] * al + sum;
      mm[m] = mn;
      al2[m] = al;
    }
#pragma unroll
    for (int m = 0; m < 2; m++)
#pragma unroll
      for (int c = 0; c < 4; c++)
#pragma unroll
        for (int r = 0; r < 4; r++) o[m][c][r] *= al2[m];
    // ---- PV: P^T from per-wave LDS as B-operand; V^T rows as A (transient)
    bf16x8 bp[2][2];
#pragma unroll
    for (int m = 0; m < 2; m++) {
      bp[m][0] = ld8(&Pl[plb + m * 16 * 72 + lq * 72 + quad * 8]);
      bp[m][1] = ld8(&Pl[plb + m * 16 * 72 + lq * 72 + 32 + quad * 8]);
    }
#pragma unroll
    for (int c = 0; c < 4; c++) {
      const bf16* vr = VT + (c * 16 + lq) * SEQ + k0;
      bf16x8 av0 = ld8(vr + quad * 8);
      bf16x8 av1 = ld8(vr + 32 + quad * 8);
#pragma unroll
      for (int m = 0; m < 2; m++) {
        o[m][c] = __builtin_amdgcn_mfma_f32_16x16x32_bf16(av0, bp[m][0], o[m][c], 0, 0, 0);
        o[m][c] = __builtin_amdgcn_mfma_f32_16x16x32_bf16(av1, bp[m][1], o[m][c], 0, 0, 0);
      }
    }
  }
  // ---- merge wave1 -> wave0 (exact fp32), two phases through wave1's Pl ----
  float* mrg = reinterpret_cast<float*>(&Pl[2 * 16 * 72]);  // 4096B o + 128B ml
  float* mlf = mrg + 1024;
  bf16* ar = ws + OFF_ATT;
  int b = bh >> 4, h = bh & 15;
#pragma unroll
  for (int m = 0; m < 2; m++) {
    if (widx == 1) {
#pragma unroll
      for (int c = 0; c < 4; c++)
        *reinterpret_cast<f32x4*>(&mrg[(c * 64 + lane) * 4]) = o[m][c];
      if (quad == 0) { mlf[lq * 2] = mm[m]; mlf[lq * 2 + 1] = ll[m]; }
    }
    __syncthreads();
    if (widx == 0) {
      float mB = mlf[lq * 2], lB = mlf[lq * 2 + 1];
      float mn = fmaxf(mm[m], mB);
      float a = exp2f((mm[m] - mn) * SSCALE);
      float bb = exp2f((mB - mn) * SSCALE);
      float linv = 1.0f / (ll[m] * a + lB * bb);
      size_t rowoff = ((size_t)(b * SEQ + qw + m * 16 + lq)) * DINNER + h * HDIM;
#pragma unroll
      for (int c = 0; c < 4; c++) {
        f32x4 ob = *reinterpret_cast<f32x4*>(&mrg[(c * 64 + lane) * 4]);
        bf16x4 ov = {(bf16)((o[m][c][0] * a + ob[0] * bb) * linv),
                     (bf16)((o[m][c][1] * a + ob[1] * bb) * linv),
                     (bf16)((o[m][c][2] * a + ob[2] * bb) * linv),
                     (bf16)((o[m][c][3] * a + ob[3] * bb) * linv)};
        *reinterpret_cast<bf16x4*>(&ar[rowoff + c * 16 + quad * 4]) = ov;
      }
    }
    __syncthreads();
  }
}

// ---------------- kernel 4: output projection, 4-wave split-K --------------
__global__ __launch_bounds__(256) void oproj_kernel(const bf16* __restrict__ ws,
                                                    const int* __restrict__ flag,
                                                    void* __restrict__ outp) {
  __shared__ __align__(16) float red[3 * 64 * 16];  // 12 KB
  int isbf = *flag;
  int tt = blockIdx.x;
  int w = threadIdx.x >> 6;
  int lane = threadIdx.x & 63;
  int lq = lane & 15, quad = lane >> 4;
  const bf16* A = ws + OFF_ATT + (size_t)(tt * 16 + lq) * DINNER;
  const bf16* WoT = ws + OFF_WOT;
  f32x4 acc[4];
#pragma unroll
  for (int c = 0; c < 4; c++) acc[c] = (f32x4){0.f, 0.f, 0.f, 0.f};
  int kbeg = w * 256;
  for (int k0 = kbeg; k0 < kbeg + 256; k0 += 32) {
    bf16x8 a = ld8(A + k0 + quad * 8);
#pragma unroll
    for (int c = 0; c < 4; c++) {
      bf16x8 b = ld8(WoT + (size_t)(c * 16 + lq) * DINNER + k0 + quad * 8);
      acc[c] = __builtin_amdgcn_mfma_f32_16x16x32_bf16(a, b, acc[c], 0, 0, 0);
    }
  }
  if (w > 0) {
#pragma unroll
    for (int c = 0; c < 4; c++)
      *reinterpret_cast<f32x4*>(&red[(((w - 1) * 64 + lane) * 4 + c) * 4]) = acc[c];
  }
  __syncthreads();
  if (w == 0) {
#pragma unroll
    for (int j = 0; j < 3; j++)
#pragma unroll
      for (int c = 0; c < 4; c++)
        acc[c] += *reinterpret_cast<f32x4*>(&red[((j * 64 + lane) * 4 + c) * 4]);
#pragma unroll
    for (int c = 0; c < 4; c++) {
      float bv = (float)ws[OFF_BO + c * 16 + lq];
#pragma unroll
      for (int r = 0; r < 4; r++) {
        int t = tt * 16 + quad * 4 + r;
        float v = acc[c][r] + bv;
        size_t oo = (size_t)t * HDIM + c * 16 + lq;
        if (isbf) ((bf16*)outp)[oo] = (bf16)v;
        else      ((float*)outp)[oo] = v;
      }
    }
  }
}

extern "C" void kernel_launch(void* const* d_in, const int* in_sizes, int n_in,
                              void* d_out, int out_size, void* d_ws, size_t ws_size,
                              hipStream_t stream) {
  const void* x  = d_in[0];
  const void* Wq = d_in[1];
  const void* Wk = d_in[2];
  const void* Wv = d_in[3];
  const void* Wo = d_in[4];
  const void* bo = d_in[5];
  const int* cm  = (const int*)d_in[6];
  bf16* ws = (bf16*)d_ws;
  int* flag = (int*)d_ws;

  hipLaunchKernelGGL(detect_kernel, dim3(1), dim3(64), 0, stream,
                     (const unsigned short*)x, flag);
  hipLaunchKernelGGL(prep_kernel, dim3(256, 13), dim3(256), 0, stream,
                     x, Wq, Wk, Wv, Wo, bo, flag, ws);
  hipLaunchKernelGGL(qkv_kernel, dim3(128, 4, 3), dim3(256), 0, stream, ws);
  hipLaunchKernelGGL(flash_kernel, dim3(4096), dim3(128), 0, stream, cm, ws);
  hipLaunchKernelGGL(oproj_kernel, dim3(512), dim3(256), 0, stream, ws, flag, d_out);
}